// Round 8
// baseline (194.964 us; speedup 1.0000x reference)
//
#include <hip/hip_runtime.h>
#include <hip/hip_bf16.h>
#include <hip/hip_fp16.h>

#define N_NODES  100000
#define N_RADIAL 16
#define N_CONICAL 16

#define NPB    256                                   // nodes per bucket
#define NBKT   ((N_NODES + NPB - 1) / NPB)           // 391 buckets
#define NBLK_A 256                                   // binning blocks
#define BTHR   512                                   // binning block threads
#define HTOT   (NBKT * NBLK_A)                       // 100,096 hist entries
#define SCAN_BLK 1024
#define NB1    ((HTOT + SCAN_BLK - 1) / SCAN_BLK)    // 98
#define CAP    14336                                 // bucket edge capacity

// ---------------------------------------------------------------------------
// P. Pack conical half of x to f16 (3.2 MB -> per-XCD-L2-resident; verified
//    R6: FETCH 148->19.6 MB).
// ---------------------------------------------------------------------------
__global__ __launch_bounds__(256) void pack_kernel(
    const float* __restrict__ x, __half2* __restrict__ xcon2) {
    int t = blockIdx.x * 256 + threadIdx.x;
    if (t >= N_NODES * 8) return;
    int n = t >> 3, p = t & 7;
    const float2* xp = (const float2*)x;
    float2 v = xp[n * 16 + 8 + p];
    xcon2[t] = __floats2half2_rn(v.x, v.y);
}

// ---------------------------------------------------------------------------
// A1. Per-block bucket histogram (bucket = row>>8).
// ---------------------------------------------------------------------------
__global__ __launch_bounds__(BTHR) void hist_kernel(
    const int* __restrict__ idx, int* __restrict__ hist,
    int chunk, int total) {
    __shared__ int lh[NBKT];
    int b = blockIdx.x, tid = threadIdx.x;
    for (int i = tid; i < NBKT; i += BTHR) lh[i] = 0;
    __syncthreads();
    int lo = b * chunk;
    int hi = min(lo + chunk, total);
    for (int d = lo + tid; d < hi; d += BTHR)
        atomicAdd(&lh[idx[d] >> 8], 1);
    __syncthreads();
    for (int i = tid; i < NBKT; i += BTHR)
        hist[i * NBLK_A + b] = lh[i];
}

// ---------------------------------------------------------------------------
// A2. 3-kernel exclusive scan over hist -> hoff.
// ---------------------------------------------------------------------------
__global__ __launch_bounds__(SCAN_BLK) void scan1_kernel(
    const int* __restrict__ in, int* __restrict__ out,
    int* __restrict__ bsum, int n) {
    __shared__ int s[SCAN_BLK];
    int t = threadIdx.x, i = blockIdx.x * SCAN_BLK + t;
    int v = (i < n) ? in[i] : 0;
    s[t] = v;
    for (int off = 1; off < SCAN_BLK; off <<= 1) {
        __syncthreads();
        int y = (t >= off) ? s[t - off] : 0;
        __syncthreads();
        s[t] += y;
    }
    if (i < n) out[i] = s[t] - v;
    if (t == SCAN_BLK - 1) bsum[blockIdx.x] = s[t];
}

__global__ __launch_bounds__(256) void scan2_kernel(int* __restrict__ bsum, int nb) {
    __shared__ int s[256];
    int t = threadIdx.x;
    int v = (t < nb) ? bsum[t] : 0;
    s[t] = v;
    for (int off = 1; off < 256; off <<= 1) {
        __syncthreads();
        int y = (t >= off) ? s[t - off] : 0;
        __syncthreads();
        s[t] += y;
    }
    if (t < nb) bsum[t] = s[t] - v;
}

__global__ __launch_bounds__(SCAN_BLK) void scan3_kernel(
    int* __restrict__ out, const int* __restrict__ bsum, int n) {
    int i = blockIdx.x * SCAN_BLK + threadIdx.x;
    if (i < n) out[i] += bsum[blockIdx.x];
}

// ---------------------------------------------------------------------------
// A3. Bin-scatter: packed (row_local<<17 | col) grouped by bucket.
// ---------------------------------------------------------------------------
__global__ __launch_bounds__(BTHR) void bin_kernel(
    const int* __restrict__ idx, const int* __restrict__ hoff,
    unsigned int* __restrict__ binned, int chunk, int total, int E) {
    __shared__ int cur[NBKT];
    int b = blockIdx.x, tid = threadIdx.x;
    for (int i = tid; i < NBKT; i += BTHR)
        cur[i] = hoff[i * NBLK_A + b];
    __syncthreads();
    int lo = b * chunk;
    int hi = min(lo + chunk, total);
    for (int d = lo + tid; d < hi; d += BTHR) {
        int row = idx[d];
        int col = (d < E) ? idx[d + E] : idx[d - E];
        int p = atomicAdd(&cur[row >> 8], 1);
        binned[p] = ((unsigned int)(row & 255) << 17) | (unsigned int)col;
    }
}

// ---------------------------------------------------------------------------
// B. Bucket accumulate (R7, verified): in-block counting sort (2 LDS
//    atomics/edge), then atomic-free register accumulation; quad per node,
//    lane q owns channels 4q..4q+3.
// ---------------------------------------------------------------------------
__global__ __launch_bounds__(1024, 2) void agg_kernel(
    const __half* __restrict__ xcon, const int* __restrict__ hoff,
    const unsigned int* __restrict__ binned, __half* __restrict__ agg,
    int total) {
    __shared__ unsigned int sedge[CAP];   // 56 KB
    __shared__ int scnt[NPB];
    __shared__ int soff[NPB];
    int b = blockIdx.x, tid = threadIdx.x;
    if (tid < NPB) scnt[tid] = 0;
    __syncthreads();

    int start = hoff[b * NBLK_A];
    int end   = (b == NBKT - 1) ? total : hoff[(b + 1) * NBLK_A];

    unsigned int held[14];
    #pragma unroll
    for (int it = 0; it < 14; it++) {
        int e = start + tid + it * 1024;
        unsigned int p = 0xFFFFFFFFu;
        if (e < end) {
            p = binned[e];
            atomicAdd(&scnt[p >> 17], 1);
        }
        held[it] = p;
    }
    __syncthreads();

    if (tid < NPB) soff[tid] = scnt[tid];
    __syncthreads();
    for (int off = 1; off < NPB; off <<= 1) {
        int y = 0;
        if (tid < NPB && tid >= off) y = soff[tid - off];
        __syncthreads();
        if (tid < NPB) soff[tid] += y;
        __syncthreads();
    }
    if (tid < NPB) soff[tid] -= scnt[tid];
    __syncthreads();

    #pragma unroll
    for (int it = 0; it < 14; it++) {
        unsigned int p = held[it];
        if (p != 0xFFFFFFFFu) {
            int pos = atomicAdd(&soff[p >> 17], 1);
            sedge[pos] = p & 0x1FFFFu;
        }
    }
    __syncthreads();

    int nl = tid >> 2, q = tid & 3;
    int c  = scnt[nl];
    int s0 = soff[nl] - c;
    float a0 = 0.f, a1 = 0.f, a2 = 0.f, a3 = 0.f;
    #pragma unroll 4
    for (int k = 0; k < c; k++) {
        int col = (int)sedge[s0 + k];
        uint2 raw = ((const uint2*)(xcon + (size_t)col * 16))[q];
        float2 f0 = __half22float2(*(const __half2*)&raw.x);
        float2 f1 = __half22float2(*(const __half2*)&raw.y);
        a0 += f0.x; a1 += f0.y; a2 += f1.x; a3 += f1.y;
    }
    int n = b * NPB + nl;
    if (n < N_NODES) {
        float inv = 1.0f / (float)max(c, 1);
        __half2 h0 = __floats2half2_rn(a0 * inv, a1 * inv);
        __half2 h1 = __floats2half2_rn(a2 * inv, a3 * inv);
        uint2 st;
        st.x = *(unsigned int*)&h0;
        st.y = *(unsigned int*)&h1;
        *(uint2*)(agg + (size_t)n * 16 + q * 4) = st;
    }
}

// ---------------------------------------------------------------------------
// W. Transpose W1 (32x128 -> [k][c], 16 KB) into the hoff region (dead
//    after agg) so mlp's layer-1 weight reads are contiguous per k.
// ---------------------------------------------------------------------------
__global__ __launch_bounds__(256) void wt_kernel(
    const float* __restrict__ W1, float* __restrict__ W1t) {
    int i = blockIdx.x * 256 + threadIdx.x;      // 4096 elements
    int c = i >> 7, k = i & 127;
    W1t[k * 32 + c] = W1[i];
}

// ---------------------------------------------------------------------------
// C. MLP v3 — zero LDS. R7 counters proved LDS-read-throughput bound
//    (VALUBusy 30% = 256/768 cyc; 16 ds_read_b128/k/wave on the shared LDS
//    pipe). Weight addresses are wave-uniform -> compiler emits s_load on
//    the scalar pipe; v_fma takes the SGPR operand directly. 64-thr blocks
//    x 1563 -> ~6 blocks/CU (R7's 196 blocks idled 60 CUs). 4-way partial
//    sums break the h dependency chain.
// ---------------------------------------------------------------------------
__global__ __launch_bounds__(64, 4) void mlp_kernel(
    const float* __restrict__ x, const __half* __restrict__ agg,
    const float* __restrict__ W1t, const float* __restrict__ b1,
    const float* __restrict__ W2, const float* __restrict__ b2,
    float* __restrict__ out, int N) {
    int n = blockIdx.x * 64 + threadIdx.x;
    if (n >= N) return;

    float comb[32];
    const float4* xr = (const float4*)(x + (size_t)n * 32);
    #pragma unroll
    for (int c = 0; c < 4; c++) {
        float4 v = xr[c];
        comb[c * 4 + 0] = v.x; comb[c * 4 + 1] = v.y;
        comb[c * 4 + 2] = v.z; comb[c * 4 + 3] = v.w;
    }
    const __half2* ar = (const __half2*)(agg + (size_t)n * 16);
    #pragma unroll
    for (int c = 0; c < 8; c++) {
        float2 f = __half22float2(ar[c]);
        comb[N_RADIAL + 2 * c]     = f.x;
        comb[N_RADIAL + 2 * c + 1] = f.y;
    }

    float acc[32];
    #pragma unroll
    for (int o = 0; o < 32; o++) acc[o] = b2[o];      // uniform -> s_load

    #pragma unroll 4
    for (int k = 0; k < 128; k++) {
        const float* w1 = W1t + k * 32;               // uniform base
        float h0 = 0.f, h1 = 0.f, h2 = 0.f, h3 = 0.f;
        #pragma unroll
        for (int c = 0; c < 8; c++) {
            h0 = fmaf(comb[4 * c + 0], w1[4 * c + 0], h0);
            h1 = fmaf(comb[4 * c + 1], w1[4 * c + 1], h1);
            h2 = fmaf(comb[4 * c + 2], w1[4 * c + 2], h2);
            h3 = fmaf(comb[4 * c + 3], w1[4 * c + 3], h3);
        }
        float h = fmaxf((h0 + h1) + (h2 + h3) + b1[k], 0.0f);
        const float* w2 = W2 + k * 32;                // uniform base
        #pragma unroll
        for (int o = 0; o < 32; o++)
            acc[o] = fmaf(h, w2[o], acc[o]);
    }

    float4* op = (float4*)(out + (size_t)n * 32);
    #pragma unroll
    for (int o = 0; o < 8; o++)
        op[o] = make_float4(acc[4 * o], acc[4 * o + 1], acc[4 * o + 2], acc[4 * o + 3]);
}

extern "C" void kernel_launch(void* const* d_in, const int* in_sizes, int n_in,
                              void* d_out, int out_size, void* d_ws, size_t ws_size,
                              hipStream_t stream) {
    const float* x   = (const float*)d_in[0];
    const int*   idx = (const int*)d_in[1];
    const float* W1  = (const float*)d_in[2];
    const float* b1  = (const float*)d_in[3];
    const float* W2  = (const float*)d_in[4];
    const float* b2  = (const float*)d_in[5];
    float* out = (float*)d_out;

    const int E = in_sizes[1] / 2;     // 1,600,000
    const int total = 2 * E;           // 3,200,000
    const int chunk = (total + NBLK_A - 1) / NBLK_A;   // 12,500

    // ws layout (6.81 MB, same as R6/R7):
    //   region0 3.203 MB: hist (early) -> agg f16 (late)
    //   hoff 400 KB (dead after agg -> W1t overlay, 16 KB) | bsum | xcon 3.2 MB
    char* base = (char*)d_ws;
    int*    hist = (int*)base;
    __half* agg  = (__half*)base;
    int*    hoff = (int*)(base + 3203072);
    float*  W1t  = (float*)(base + 3203072);           // overlays hoff (late)
    int*    bsum = (int*)(base + 3203072 + 400384);
    __half* xcon = (__half*)(base + 3203072 + 400384 + 4096);
    // binned (12.8 MB) in d_out: consumed by agg before mlp overwrites it.
    unsigned int* binned = (unsigned int*)d_out;

    pack_kernel<<<(N_NODES * 8 + 255) / 256, 256, 0, stream>>>(
        x, (__half2*)xcon);
    hist_kernel<<<NBLK_A, BTHR, 0, stream>>>(idx, hist, chunk, total);
    scan1_kernel<<<NB1, SCAN_BLK, 0, stream>>>(hist, hoff, bsum, HTOT);
    scan2_kernel<<<1, 256, 0, stream>>>(bsum, NB1);
    scan3_kernel<<<NB1, SCAN_BLK, 0, stream>>>(hoff, bsum, HTOT);
    bin_kernel<<<NBLK_A, BTHR, 0, stream>>>(idx, hoff, binned, chunk, total, E);
    agg_kernel<<<NBKT, 1024, 0, stream>>>(xcon, hoff, binned, agg, total);
    wt_kernel<<<16, 256, 0, stream>>>(W1, W1t);        // hoff now dead
    mlp_kernel<<<(N_NODES + 63) / 64, 64, 0, stream>>>(
        x, agg, W1t, b1, W2, b2, out, N_NODES);
}

// Round 9
// 169.831 us; speedup vs baseline: 1.1480x; 1.1480x over previous
//
#include <hip/hip_runtime.h>
#include <hip/hip_bf16.h>
#include <hip/hip_fp16.h>

#define N_NODES  100000
#define N_RADIAL 16
#define N_CONICAL 16

#define NPB    256                                   // nodes per bucket
#define NBKT   ((N_NODES + NPB - 1) / NPB)           // 391 buckets
#define NBLK_A 256                                   // binning blocks
#define BTHR   512                                   // binning block threads
#define HTOT   (NBKT * NBLK_A)                       // 100,096 hist entries
#define SCAN_BLK 1024
#define NB1    ((HTOT + SCAN_BLK - 1) / SCAN_BLK)    // 98
#define CAP    14336                                 // bucket edge capacity

// ---------------------------------------------------------------------------
// P. Pack conical half of x to f16 (3.2 MB -> per-XCD-L2-resident; verified
//    R6: FETCH 148->19.6 MB).
// ---------------------------------------------------------------------------
__global__ __launch_bounds__(256) void pack_kernel(
    const float* __restrict__ x, __half2* __restrict__ xcon2) {
    int t = blockIdx.x * 256 + threadIdx.x;
    if (t >= N_NODES * 8) return;
    int n = t >> 3, p = t & 7;
    const float2* xp = (const float2*)x;
    float2 v = xp[n * 16 + 8 + p];
    xcon2[t] = __floats2half2_rn(v.x, v.y);
}

// ---------------------------------------------------------------------------
// A1. Per-block bucket histogram (bucket = row>>8).
// ---------------------------------------------------------------------------
__global__ __launch_bounds__(BTHR) void hist_kernel(
    const int* __restrict__ idx, int* __restrict__ hist,
    int chunk, int total) {
    __shared__ int lh[NBKT];
    int b = blockIdx.x, tid = threadIdx.x;
    for (int i = tid; i < NBKT; i += BTHR) lh[i] = 0;
    __syncthreads();
    int lo = b * chunk;
    int hi = min(lo + chunk, total);
    for (int d = lo + tid; d < hi; d += BTHR)
        atomicAdd(&lh[idx[d] >> 8], 1);
    __syncthreads();
    for (int i = tid; i < NBKT; i += BTHR)
        hist[i * NBLK_A + b] = lh[i];
}

// ---------------------------------------------------------------------------
// A2. 3-kernel exclusive scan over hist -> hoff.
// ---------------------------------------------------------------------------
__global__ __launch_bounds__(SCAN_BLK) void scan1_kernel(
    const int* __restrict__ in, int* __restrict__ out,
    int* __restrict__ bsum, int n) {
    __shared__ int s[SCAN_BLK];
    int t = threadIdx.x, i = blockIdx.x * SCAN_BLK + t;
    int v = (i < n) ? in[i] : 0;
    s[t] = v;
    for (int off = 1; off < SCAN_BLK; off <<= 1) {
        __syncthreads();
        int y = (t >= off) ? s[t - off] : 0;
        __syncthreads();
        s[t] += y;
    }
    if (i < n) out[i] = s[t] - v;
    if (t == SCAN_BLK - 1) bsum[blockIdx.x] = s[t];
}

__global__ __launch_bounds__(256) void scan2_kernel(int* __restrict__ bsum, int nb) {
    __shared__ int s[256];
    int t = threadIdx.x;
    int v = (t < nb) ? bsum[t] : 0;
    s[t] = v;
    for (int off = 1; off < 256; off <<= 1) {
        __syncthreads();
        int y = (t >= off) ? s[t - off] : 0;
        __syncthreads();
        s[t] += y;
    }
    if (t < nb) bsum[t] = s[t] - v;
}

__global__ __launch_bounds__(SCAN_BLK) void scan3_kernel(
    int* __restrict__ out, const int* __restrict__ bsum, int n) {
    int i = blockIdx.x * SCAN_BLK + threadIdx.x;
    if (i < n) out[i] += bsum[blockIdx.x];
}

// ---------------------------------------------------------------------------
// A3. Bin-scatter: packed (row_local<<17 | col) grouped by bucket.
// ---------------------------------------------------------------------------
__global__ __launch_bounds__(BTHR) void bin_kernel(
    const int* __restrict__ idx, const int* __restrict__ hoff,
    unsigned int* __restrict__ binned, int chunk, int total, int E) {
    __shared__ int cur[NBKT];
    int b = blockIdx.x, tid = threadIdx.x;
    for (int i = tid; i < NBKT; i += BTHR)
        cur[i] = hoff[i * NBLK_A + b];
    __syncthreads();
    int lo = b * chunk;
    int hi = min(lo + chunk, total);
    for (int d = lo + tid; d < hi; d += BTHR) {
        int row = idx[d];
        int col = (d < E) ? idx[d + E] : idx[d - E];
        int p = atomicAdd(&cur[row >> 8], 1);
        binned[p] = ((unsigned int)(row & 255) << 17) | (unsigned int)col;
    }
}

// ---------------------------------------------------------------------------
// B. Bucket accumulate (R7, verified): in-block counting sort (2 LDS
//    atomics/edge), then atomic-free register accumulation; quad per node,
//    lane q owns channels 4q..4q+3.
// ---------------------------------------------------------------------------
__global__ __launch_bounds__(1024, 2) void agg_kernel(
    const __half* __restrict__ xcon, const int* __restrict__ hoff,
    const unsigned int* __restrict__ binned, __half* __restrict__ agg,
    int total) {
    __shared__ unsigned int sedge[CAP];   // 56 KB
    __shared__ int scnt[NPB];
    __shared__ int soff[NPB];
    int b = blockIdx.x, tid = threadIdx.x;
    if (tid < NPB) scnt[tid] = 0;
    __syncthreads();

    int start = hoff[b * NBLK_A];
    int end   = (b == NBKT - 1) ? total : hoff[(b + 1) * NBLK_A];

    unsigned int held[14];
    #pragma unroll
    for (int it = 0; it < 14; it++) {
        int e = start + tid + it * 1024;
        unsigned int p = 0xFFFFFFFFu;
        if (e < end) {
            p = binned[e];
            atomicAdd(&scnt[p >> 17], 1);
        }
        held[it] = p;
    }
    __syncthreads();

    if (tid < NPB) soff[tid] = scnt[tid];
    __syncthreads();
    for (int off = 1; off < NPB; off <<= 1) {
        int y = 0;
        if (tid < NPB && tid >= off) y = soff[tid - off];
        __syncthreads();
        if (tid < NPB) soff[tid] += y;
        __syncthreads();
    }
    if (tid < NPB) soff[tid] -= scnt[tid];
    __syncthreads();

    #pragma unroll
    for (int it = 0; it < 14; it++) {
        unsigned int p = held[it];
        if (p != 0xFFFFFFFFu) {
            int pos = atomicAdd(&soff[p >> 17], 1);
            sedge[pos] = p & 0x1FFFFu;
        }
    }
    __syncthreads();

    int nl = tid >> 2, q = tid & 3;
    int c  = scnt[nl];
    int s0 = soff[nl] - c;
    float a0 = 0.f, a1 = 0.f, a2 = 0.f, a3 = 0.f;
    #pragma unroll 4
    for (int k = 0; k < c; k++) {
        int col = (int)sedge[s0 + k];
        uint2 raw = ((const uint2*)(xcon + (size_t)col * 16))[q];
        float2 f0 = __half22float2(*(const __half2*)&raw.x);
        float2 f1 = __half22float2(*(const __half2*)&raw.y);
        a0 += f0.x; a1 += f0.y; a2 += f1.x; a3 += f1.y;
    }
    int n = b * NPB + nl;
    if (n < N_NODES) {
        float inv = 1.0f / (float)max(c, 1);
        __half2 h0 = __floats2half2_rn(a0 * inv, a1 * inv);
        __half2 h1 = __floats2half2_rn(a2 * inv, a3 * inv);
        uint2 st;
        st.x = *(unsigned int*)&h0;
        st.y = *(unsigned int*)&h1;
        *(uint2*)(agg + (size_t)n * 16 + q * 4) = st;
    }
}

// ---------------------------------------------------------------------------
// W. Weight transposes into the hoff region (dead after agg):
//    W1t[k][c] (layer-1 rows contiguous), W2t[o][k] (layer-2 rows contiguous).
// ---------------------------------------------------------------------------
__global__ __launch_bounds__(256) void wt_kernel(
    const float* __restrict__ W1, const float* __restrict__ W2,
    float* __restrict__ W1t, float* __restrict__ W2t) {
    int i = blockIdx.x * 256 + threadIdx.x;      // 4096 elements each
    int c = i >> 7, k = i & 127;
    W1t[k * 32 + c] = W1[i];                     // W1[c][k] -> W1t[k][c]
    int kk = i >> 5, o = i & 31;
    W2t[o * 128 + kk] = W2[i];                   // W2[k][o] -> W2t[o][k]
}

// ---------------------------------------------------------------------------
// C. MLP v5 — fused two-phase, 8 waves per 64-node tile.
//    R8 failed on geometry: 1 thread/node = 1563 waves = 1.5/SIMD, zero
//    latency hiding (VALUBusy 17%, occ 15%). v5: block=512 owns 64 nodes;
//    phase A: wave ws computes h[k=ws*16..+15] for all 64 nodes (k wave-
//    uniform via readfirstlane -> W1t on the scalar pipe), h-pairs packed
//    f16 into LDS H2[kp][node] (lane=node -> conflict-free b32).
//    phase B: wave ws computes outs o=ws*4..+3 for all 64 nodes from H2 +
//    s_load'ed W2t. 12500 waves = 12/SIMD; <=16 live acc floats per phase.
// ---------------------------------------------------------------------------
__global__ __launch_bounds__(512, 4) void mlp_kernel(
    const float* __restrict__ x, const __half* __restrict__ agg,
    const float* __restrict__ W1t, const float* __restrict__ b1,
    const float* __restrict__ W2t, const float* __restrict__ b2,
    float* __restrict__ out, int N) {
    __shared__ __half2 H2[64 * 64];   // [kp][node], 16 KB
    int tid  = threadIdx.x;
    int lane = tid & 63;                                   // node within tile
    int ws   = __builtin_amdgcn_readfirstlane(tid >> 6);   // wave slice 0..7
    int n    = blockIdx.x * 64 + lane;
    int nc   = min(n, N - 1);

    // combined = [x[:,:16], agg] — all 8 waves read the same 64 nodes
    // (redundant reads are L1/L2 hits; unique traffic unchanged)
    float comb[32];
    const float4* xr = (const float4*)(x + (size_t)nc * 32);
    #pragma unroll
    for (int c = 0; c < 4; c++) {
        float4 v = xr[c];
        comb[c*4+0] = v.x; comb[c*4+1] = v.y;
        comb[c*4+2] = v.z; comb[c*4+3] = v.w;
    }
    const __half2* ar = (const __half2*)(agg + (size_t)nc * 16);
    #pragma unroll
    for (int c = 0; c < 8; c++) {
        float2 f = __half22float2(ar[c]);
        comb[16 + 2*c]     = f.x;
        comb[16 + 2*c + 1] = f.y;
    }

    // phase A: 16 hidden units per wave, pairs packed to f16
    #pragma unroll
    for (int i = 0; i < 16; i += 2) {
        int k0 = ws * 16 + i;                    // wave-uniform
        const float* w1a = W1t + k0 * 32;
        const float* w1b = w1a + 32;
        float ha = b1[k0], hb = b1[k0 + 1];
        #pragma unroll
        for (int c = 0; c < 32; c++) {
            ha = fmaf(comb[c], w1a[c], ha);
            hb = fmaf(comb[c], w1b[c], hb);
        }
        ha = fmaxf(ha, 0.f); hb = fmaxf(hb, 0.f);
        H2[(k0 >> 1) * 64 + lane] = __floats2half2_rn(ha, hb);
    }
    __syncthreads();

    // phase B: 4 outputs per wave across all 64 nodes
    int o0 = ws * 4;                             // wave-uniform
    const float* w20 = W2t + (o0 + 0) * 128;
    const float* w21 = W2t + (o0 + 1) * 128;
    const float* w22 = W2t + (o0 + 2) * 128;
    const float* w23 = W2t + (o0 + 3) * 128;
    float acc0 = b2[o0+0], acc1 = b2[o0+1], acc2 = b2[o0+2], acc3 = b2[o0+3];
    #pragma unroll 8
    for (int kp = 0; kp < 64; kp++) {
        float2 h = __half22float2(H2[kp * 64 + lane]);
        int k0 = 2 * kp;
        acc0 = fmaf(h.x, w20[k0], acc0); acc0 = fmaf(h.y, w20[k0+1], acc0);
        acc1 = fmaf(h.x, w21[k0], acc1); acc1 = fmaf(h.y, w21[k0+1], acc1);
        acc2 = fmaf(h.x, w22[k0], acc2); acc2 = fmaf(h.y, w22[k0+1], acc2);
        acc3 = fmaf(h.x, w23[k0], acc3); acc3 = fmaf(h.y, w23[k0+1], acc3);
    }
    if (n < N) {
        float* op = out + (size_t)n * 32 + o0;
        op[0] = acc0; op[1] = acc1; op[2] = acc2; op[3] = acc3;
    }
}

extern "C" void kernel_launch(void* const* d_in, const int* in_sizes, int n_in,
                              void* d_out, int out_size, void* d_ws, size_t ws_size,
                              hipStream_t stream) {
    const float* x   = (const float*)d_in[0];
    const int*   idx = (const int*)d_in[1];
    const float* W1  = (const float*)d_in[2];
    const float* b1  = (const float*)d_in[3];
    const float* W2  = (const float*)d_in[4];
    const float* b2  = (const float*)d_in[5];
    float* out = (float*)d_out;

    const int E = in_sizes[1] / 2;     // 1,600,000
    const int total = 2 * E;           // 3,200,000
    const int chunk = (total + NBLK_A - 1) / NBLK_A;   // 12,500

    // ws layout (6.81 MB, same as R6-R8):
    //   region0 3.203 MB: hist (early) -> agg f16 (late)
    //   hoff 400 KB (dead after agg -> W1t 16 KB + W2t 16 KB) | bsum | xcon
    char* base = (char*)d_ws;
    int*    hist = (int*)base;
    __half* agg  = (__half*)base;
    int*    hoff = (int*)(base + 3203072);
    float*  W1t  = (float*)(base + 3203072);           // overlays hoff (late)
    float*  W2t  = (float*)(base + 3203072 + 16384);
    int*    bsum = (int*)(base + 3203072 + 400384);
    __half* xcon = (__half*)(base + 3203072 + 400384 + 4096);
    // binned (12.8 MB) in d_out: consumed by agg before mlp overwrites it.
    unsigned int* binned = (unsigned int*)d_out;

    pack_kernel<<<(N_NODES * 8 + 255) / 256, 256, 0, stream>>>(
        x, (__half2*)xcon);
    hist_kernel<<<NBLK_A, BTHR, 0, stream>>>(idx, hist, chunk, total);
    scan1_kernel<<<NB1, SCAN_BLK, 0, stream>>>(hist, hoff, bsum, HTOT);
    scan2_kernel<<<1, 256, 0, stream>>>(bsum, NB1);
    scan3_kernel<<<NB1, SCAN_BLK, 0, stream>>>(hoff, bsum, HTOT);
    bin_kernel<<<NBLK_A, BTHR, 0, stream>>>(idx, hoff, binned, chunk, total, E);
    agg_kernel<<<NBKT, 1024, 0, stream>>>(xcon, hoff, binned, agg, total);
    wt_kernel<<<16, 256, 0, stream>>>(W1, W2, W1t, W2t);   // hoff now dead
    mlp_kernel<<<(N_NODES + 63) / 64, 512, 0, stream>>>(
        x, agg, W1t, b1, W2t, b2, out, N_NODES);
}

// Round 10
// 163.673 us; speedup vs baseline: 1.1912x; 1.0376x over previous
//
#include <hip/hip_runtime.h>
#include <hip/hip_bf16.h>
#include <hip/hip_fp16.h>

#define N_NODES  100000
#define N_RADIAL 16
#define N_CONICAL 16

#define NPB    256                                   // nodes per bucket
#define NBKT   ((N_NODES + NPB - 1) / NPB)           // 391 buckets
#define NBLK_A 256                                   // binning blocks
#define BTHR   512                                   // binning block threads
#define CAPB   10240                                 // per-bucket capacity (mean 8192, sd~90 -> 22 sigma)
#define CAP    14336                                 // agg LDS edge capacity

// ---------------------------------------------------------------------------
// P. Fused prep: W1/W2 transposes + gcnt zero + xcon f16 pack.
//    (R9 showed 9 launches; folding 3 tiny kernels into one.)
//    blocks 0..15: weight transposes; 16..17: zero gcnt; 18..: pack xcon.
// ---------------------------------------------------------------------------
__global__ __launch_bounds__(256) void prep_kernel(
    const float* __restrict__ x, __half2* __restrict__ xcon2,
    const float* __restrict__ W1, const float* __restrict__ W2,
    float* __restrict__ W1t, float* __restrict__ W2t,
    int* __restrict__ gcnt) {
    int b = blockIdx.x, tid = threadIdx.x;
    if (b < 16) {
        int i = b * 256 + tid;                 // 4096 weight elements
        int c = i >> 7, k = i & 127;
        W1t[k * 32 + c] = W1[i];               // W1[c][k] -> W1t[k][c]
        int kk = i >> 5, o = i & 31;
        W2t[o * 128 + kk] = W2[i];             // W2[k][o] -> W2t[o][k]
    } else if (b < 18) {
        int i = (b - 16) * 256 + tid;
        if (i < NBKT) gcnt[i] = 0;
    } else {
        int t = (b - 18) * 256 + tid;          // one half2 per thread
        if (t < N_NODES * 8) {
            int n = t >> 3, p = t & 7;
            const float2* xp = (const float2*)x;
            float2 v = xp[n * 16 + 8 + p];     // conical half
            xcon2[t] = __floats2half2_rn(v.x, v.y);
        }
    }
}

// ---------------------------------------------------------------------------
// A. Fused bin (replaces R9's hist + 3 scans + bin: 5 kernels -> 1).
//    Pass 1: per-bucket counts in LDS (3.2M LDS atomics, same as hist).
//    Reserve: one global atomicAdd per (block,bucket) into gcnt -> base.
//    Pass 2: scatter packed (row_local<<17|col) via LDS cursors into the
//    block's reserved run of binned[bkt*CAPB + ...] (line-dense short runs,
//    write pattern verified R4: WRITE_SIZE collapsed vs CSR fill).
// ---------------------------------------------------------------------------
__global__ __launch_bounds__(BTHR) void binfuse_kernel(
    const int* __restrict__ idx, int* __restrict__ gcnt,
    unsigned int* __restrict__ binned, int chunk, int total, int E) {
    __shared__ int lh[NBKT];      // pass-1 counts
    __shared__ int cur[NBKT];     // pass-2 cursors (seeded with global base)
    int b = blockIdx.x, tid = threadIdx.x;
    for (int i = tid; i < NBKT; i += BTHR) lh[i] = 0;
    __syncthreads();

    int lo = b * chunk;
    int hi = min(lo + chunk, total);
    for (int d = lo + tid; d < hi; d += BTHR)
        atomicAdd(&lh[idx[d] >> 8], 1);
    __syncthreads();

    for (int i = tid; i < NBKT; i += BTHR)
        cur[i] = atomicAdd(&gcnt[i], lh[i]);   // reserve run, get base
    __syncthreads();

    for (int d = lo + tid; d < hi; d += BTHR) {
        int row = idx[d];
        int col = (d < E) ? idx[d + E] : idx[d - E];
        int bkt = row >> 8;
        int p = atomicAdd(&cur[bkt], 1);
        binned[(size_t)bkt * CAPB + p] =
            ((unsigned int)(row & 255) << 17) | (unsigned int)col;
    }
}

// ---------------------------------------------------------------------------
// B. Bucket accumulate (R7-verified structure): in-block counting sort
//    (2 LDS atomics/edge), then atomic-free register accumulation; quad per
//    node, lane q owns channels 4q..4q+3. Bucket run now at fixed stride.
// ---------------------------------------------------------------------------
__global__ __launch_bounds__(1024, 2) void agg_kernel(
    const __half* __restrict__ xcon, const int* __restrict__ gcnt,
    const unsigned int* __restrict__ binned, __half* __restrict__ agg) {
    __shared__ unsigned int sedge[CAP];   // 56 KB
    __shared__ int scnt[NPB];
    __shared__ int soff[NPB];
    int b = blockIdx.x, tid = threadIdx.x;
    if (tid < NPB) scnt[tid] = 0;
    __syncthreads();

    int start = b * CAPB;
    int end   = start + gcnt[b];

    unsigned int held[14];
    #pragma unroll
    for (int it = 0; it < 14; it++) {
        int e = start + tid + it * 1024;
        unsigned int p = 0xFFFFFFFFu;
        if (e < end) {
            p = binned[e];
            atomicAdd(&scnt[p >> 17], 1);
        }
        held[it] = p;
    }
    __syncthreads();

    if (tid < NPB) soff[tid] = scnt[tid];
    __syncthreads();
    for (int off = 1; off < NPB; off <<= 1) {
        int y = 0;
        if (tid < NPB && tid >= off) y = soff[tid - off];
        __syncthreads();
        if (tid < NPB) soff[tid] += y;
        __syncthreads();
    }
    if (tid < NPB) soff[tid] -= scnt[tid];
    __syncthreads();

    #pragma unroll
    for (int it = 0; it < 14; it++) {
        unsigned int p = held[it];
        if (p != 0xFFFFFFFFu) {
            int pos = atomicAdd(&soff[p >> 17], 1);
            sedge[pos] = p & 0x1FFFFu;
        }
    }
    __syncthreads();

    int nl = tid >> 2, q = tid & 3;
    int c  = scnt[nl];
    int s0 = soff[nl] - c;
    float a0 = 0.f, a1 = 0.f, a2 = 0.f, a3 = 0.f;
    #pragma unroll 4
    for (int k = 0; k < c; k++) {
        int col = (int)sedge[s0 + k];
        uint2 raw = ((const uint2*)(xcon + (size_t)col * 16))[q];
        float2 f0 = __half22float2(*(const __half2*)&raw.x);
        float2 f1 = __half22float2(*(const __half2*)&raw.y);
        a0 += f0.x; a1 += f0.y; a2 += f1.x; a3 += f1.y;
    }
    int n = b * NPB + nl;
    if (n < N_NODES) {
        float inv = 1.0f / (float)max(c, 1);
        __half2 h0 = __floats2half2_rn(a0 * inv, a1 * inv);
        __half2 h1 = __floats2half2_rn(a2 * inv, a3 * inv);
        uint2 st;
        st.x = *(unsigned int*)&h0;
        st.y = *(unsigned int*)&h1;
        *(uint2*)(agg + (size_t)n * 16 + q * 4) = st;
    }
}

// ---------------------------------------------------------------------------
// C. MLP (R9-verified): fused two-phase, 8 waves per 64-node tile.
//    Phase A: wave ws computes h[k=ws*16..+15] for 64 nodes (k wave-uniform
//    -> W1t on the scalar pipe), h-pairs packed f16 into LDS H2[kp][node].
//    Phase B: wave ws computes outs o=ws*4..+3 from H2 + s_load'ed W2t.
//    12500 waves = 12/SIMD.
// ---------------------------------------------------------------------------
__global__ __launch_bounds__(512, 4) void mlp_kernel(
    const float* __restrict__ x, const __half* __restrict__ agg,
    const float* __restrict__ W1t, const float* __restrict__ b1,
    const float* __restrict__ W2t, const float* __restrict__ b2,
    float* __restrict__ out, int N) {
    __shared__ __half2 H2[64 * 64];   // [kp][node], 16 KB
    int tid  = threadIdx.x;
    int lane = tid & 63;
    int ws   = __builtin_amdgcn_readfirstlane(tid >> 6);
    int n    = blockIdx.x * 64 + lane;
    int nc   = min(n, N - 1);

    float comb[32];
    const float4* xr = (const float4*)(x + (size_t)nc * 32);
    #pragma unroll
    for (int c = 0; c < 4; c++) {
        float4 v = xr[c];
        comb[c*4+0] = v.x; comb[c*4+1] = v.y;
        comb[c*4+2] = v.z; comb[c*4+3] = v.w;
    }
    const __half2* ar = (const __half2*)(agg + (size_t)nc * 16);
    #pragma unroll
    for (int c = 0; c < 8; c++) {
        float2 f = __half22float2(ar[c]);
        comb[16 + 2*c]     = f.x;
        comb[16 + 2*c + 1] = f.y;
    }

    #pragma unroll
    for (int i = 0; i < 16; i += 2) {
        int k0 = ws * 16 + i;
        const float* w1a = W1t + k0 * 32;
        const float* w1b = w1a + 32;
        float ha = b1[k0], hb = b1[k0 + 1];
        #pragma unroll
        for (int c = 0; c < 32; c++) {
            ha = fmaf(comb[c], w1a[c], ha);
            hb = fmaf(comb[c], w1b[c], hb);
        }
        ha = fmaxf(ha, 0.f); hb = fmaxf(hb, 0.f);
        H2[(k0 >> 1) * 64 + lane] = __floats2half2_rn(ha, hb);
    }
    __syncthreads();

    int o0 = ws * 4;
    const float* w20 = W2t + (o0 + 0) * 128;
    const float* w21 = W2t + (o0 + 1) * 128;
    const float* w22 = W2t + (o0 + 2) * 128;
    const float* w23 = W2t + (o0 + 3) * 128;
    float acc0 = b2[o0+0], acc1 = b2[o0+1], acc2 = b2[o0+2], acc3 = b2[o0+3];
    #pragma unroll 8
    for (int kp = 0; kp < 64; kp++) {
        float2 h = __half22float2(H2[kp * 64 + lane]);
        int k0 = 2 * kp;
        acc0 = fmaf(h.x, w20[k0], acc0); acc0 = fmaf(h.y, w20[k0+1], acc0);
        acc1 = fmaf(h.x, w21[k0], acc1); acc1 = fmaf(h.y, w21[k0+1], acc1);
        acc2 = fmaf(h.x, w22[k0], acc2); acc2 = fmaf(h.y, w22[k0+1], acc2);
        acc3 = fmaf(h.x, w23[k0], acc3); acc3 = fmaf(h.y, w23[k0+1], acc3);
    }
    if (n < N) {
        float* op = out + (size_t)n * 32 + o0;
        op[0] = acc0; op[1] = acc1; op[2] = acc2; op[3] = acc3;
    }
}

extern "C" void kernel_launch(void* const* d_in, const int* in_sizes, int n_in,
                              void* d_out, int out_size, void* d_ws, size_t ws_size,
                              hipStream_t stream) {
    const float* x   = (const float*)d_in[0];
    const int*   idx = (const int*)d_in[1];
    const float* W1  = (const float*)d_in[2];
    const float* b1  = (const float*)d_in[3];
    const float* W2  = (const float*)d_in[4];
    const float* b2  = (const float*)d_in[5];
    float* out = (float*)d_out;

    const int E = in_sizes[1] / 2;     // 1,600,000
    const int total = 2 * E;           // 3,200,000
    const int chunk = (total + NBLK_A - 1) / NBLK_A;   // 12,500

    // ws layout (~22.5 MB; R9's fill proved ws_size = 256 MiB):
    //   agg f16 3.2MB | xcon f16 3.2MB | W1t 16KB | W2t 16KB | gcnt | binned 16MB
    char* base = (char*)d_ws;
    __half*       agg    = (__half*)base;
    __half*       xcon   = (__half*)(base + 3203072);
    float*        W1t    = (float*)(base + 6406144);
    float*        W2t    = (float*)(base + 6422528);
    int*          gcnt   = (int*)(base + 6438912);
    unsigned int* binned = (unsigned int*)(base + 6443008);

    prep_kernel<<<18 + (N_NODES * 8 + 255) / 256, 256, 0, stream>>>(
        x, (__half2*)xcon, W1, W2, W1t, W2t, gcnt);
    binfuse_kernel<<<NBLK_A, BTHR, 0, stream>>>(
        idx, gcnt, binned, chunk, total, E);
    agg_kernel<<<NBKT, 1024, 0, stream>>>(xcon, gcnt, binned, agg);
    mlp_kernel<<<(N_NODES + 63) / 64, 512, 0, stream>>>(
        x, agg, W1t, b1, W2t, b2, out, N_NODES);
}

// Round 11
// 159.992 us; speedup vs baseline: 1.2186x; 1.0230x over previous
//
#include <hip/hip_runtime.h>
#include <hip/hip_bf16.h>
#include <hip/hip_fp16.h>

#define N_NODES  100000
#define N_RADIAL 16
#define N_CONICAL 16

#define NPB    256                                   // nodes per bucket
#define NBKT   ((N_NODES + NPB - 1) / NPB)           // 391 buckets
#define NBLK_A 256                                   // binfuse scatter blocks
#define BTHR   512                                   // binfuse block threads
#define SUBCAP 96                                    // per-(block,bucket) sub-run cap
                                                     // mean 32, sigma 5.65 -> +11σ, P(ovf)~4e-20
#define BKTSTRIDE (NBLK_A * SUBCAP)                  // 24576 slots per bucket
#define CAP    10240                                 // compacted bucket cap in LDS (mean 8192 + 22σ)

// ---------------------------------------------------------------------------
// A. Fused bin+prep. Blocks 0..255: single-pass scatter into fixed-capacity
//    per-(block,bucket) sub-runs — 1 LDS cursor atomic + 1 line-dense write
//    per edge (R10's count pass + global reservation eliminated; per-cell
//    overflow probability ~4e-20 at cap 96). Exact sub-run lengths written
//    to cnts[bkt][block] from the final cursors.
//    Block 256: W1/W2 transposes. Blocks 257..: xcon f16 pack (3.2 MB ->
//    per-XCD-L2-resident; R6-verified FETCH collapse).
// ---------------------------------------------------------------------------
__global__ __launch_bounds__(BTHR) void binfuse_kernel(
    const int* __restrict__ idx, const float* __restrict__ x,
    __half2* __restrict__ xcon2,
    const float* __restrict__ W1, const float* __restrict__ W2,
    float* __restrict__ W1t, float* __restrict__ W2t,
    unsigned int* __restrict__ binned, int* __restrict__ cnts,
    int chunk, int total, int E) {
    int b = blockIdx.x, tid = threadIdx.x;
    if (b >= NBLK_A) {
        int pb = b - NBLK_A;
        if (pb == 0) {                       // weight transposes (4096 each)
            for (int i = tid; i < 4096; i += BTHR) {
                int c = i >> 7, k = i & 127;
                W1t[k * 32 + c] = W1[i];     // W1[c][k] -> W1t[k][c]
                int kk = i >> 5, o = i & 31;
                W2t[o * 128 + kk] = W2[i];   // W2[k][o] -> W2t[o][k]
            }
        } else {                             // xcon pack: one half2/thread
            int t = (pb - 1) * BTHR + tid;
            if (t < N_NODES * 8) {
                int n = t >> 3, p = t & 7;
                const float2* xp = (const float2*)x;
                float2 v = xp[n * 16 + 8 + p];
                xcon2[t] = __floats2half2_rn(v.x, v.y);
            }
        }
        return;
    }

    __shared__ int cur[NBKT];
    for (int i = tid; i < NBKT; i += BTHR)
        cur[i] = i * BKTSTRIDE + b * SUBCAP;       // absolute slot cursor
    __syncthreads();

    int lo = b * chunk;
    int hi = min(lo + chunk, total);
    for (int d = lo + tid; d < hi; d += BTHR) {
        int row = idx[d];
        int col = (d < E) ? idx[d + E] : idx[d - E];
        int bkt = row >> 8;
        int p = atomicAdd(&cur[bkt], 1);
        binned[p] = ((unsigned int)(row & 255) << 17) | (unsigned int)col;
    }
    __syncthreads();

    for (int i = tid; i < NBKT; i += BTHR)
        cnts[i * NBLK_A + b] = cur[i] - (i * BKTSTRIDE + b * SUBCAP);
}

// ---------------------------------------------------------------------------
// B. Bucket accumulate v3. Reads its bucket's 256 sub-runs (4 lanes each,
//    exact lengths from cnts — no sentinels), counting-sorts by local node
//    into sedge (2 LDS atomics/edge, R7-verified), then atomic-free
//    register accumulation with 2 lanes/node x 16B gathers (halves request
//    count vs R10's 4x8B).
// ---------------------------------------------------------------------------
__global__ __launch_bounds__(1024, 2) void agg_kernel(
    const __half* __restrict__ xcon, const int* __restrict__ cnts,
    const unsigned int* __restrict__ binned, __half* __restrict__ agg) {
    __shared__ unsigned int sedge[CAP];   // 40 KB
    __shared__ int scnt[NPB];
    __shared__ int soff[NPB];
    int b = blockIdx.x, tid = threadIdx.x;
    if (tid < NPB) scnt[tid] = 0;
    __syncthreads();

    int sub = tid >> 2, l = tid & 2 * 2 - 1;  // l = tid & 3
    int sc  = cnts[b * NBLK_A + sub];
    unsigned int base = (unsigned int)b * BKTSTRIDE + (unsigned int)sub * SUBCAP;

    // pass 1: per-node counts
    for (int j = l; j < sc; j += 4)
        atomicAdd(&scnt[binned[base + j] >> 17], 1);
    __syncthreads();

    // pass 2: exclusive scan (Hillis-Steele over 256)
    if (tid < NPB) soff[tid] = scnt[tid];
    __syncthreads();
    for (int off = 1; off < NPB; off <<= 1) {
        int y = 0;
        if (tid < NPB && tid >= off) y = soff[tid - off];
        __syncthreads();
        if (tid < NPB) soff[tid] += y;
        __syncthreads();
    }
    if (tid < NPB) soff[tid] -= scnt[tid];
    __syncthreads();

    // pass 3: scatter into node-sorted sedge (L2-hot re-read of sub-runs)
    for (int j = l; j < sc; j += 4) {
        unsigned int p = binned[base + j];
        int pos = atomicAdd(&soff[p >> 17], 1);
        sedge[pos] = p & 0x1FFFFu;
    }
    __syncthreads();

    // pass 4: accumulate, 2 lanes/node, 16B gathers from L2-resident xcon
    if (tid < 2 * NPB) {
        int nl = tid >> 1, q = tid & 1;
        int c  = scnt[nl];
        int s0 = soff[nl] - c;                 // soff advanced to row end
        float a0 = 0.f, a1 = 0.f, a2 = 0.f, a3 = 0.f;
        float a4 = 0.f, a5 = 0.f, a6 = 0.f, a7 = 0.f;
        #pragma unroll 2
        for (int k = 0; k < c; k++) {
            int col = (int)sedge[s0 + k];      // broadcast within pair
            uint4 raw = ((const uint4*)(xcon + (size_t)col * 16))[q];
            float2 f0 = __half22float2(*(const __half2*)&raw.x);
            float2 f1 = __half22float2(*(const __half2*)&raw.y);
            float2 f2 = __half22float2(*(const __half2*)&raw.z);
            float2 f3 = __half22float2(*(const __half2*)&raw.w);
            a0 += f0.x; a1 += f0.y; a2 += f1.x; a3 += f1.y;
            a4 += f2.x; a5 += f2.y; a6 += f3.x; a7 += f3.y;
        }
        int n = b * NPB + nl;
        if (n < N_NODES) {
            float inv = 1.0f / (float)max(c, 1);
            __half2 h0 = __floats2half2_rn(a0 * inv, a1 * inv);
            __half2 h1 = __floats2half2_rn(a2 * inv, a3 * inv);
            __half2 h2 = __floats2half2_rn(a4 * inv, a5 * inv);
            __half2 h3 = __floats2half2_rn(a6 * inv, a7 * inv);
            uint4 st;
            st.x = *(unsigned int*)&h0; st.y = *(unsigned int*)&h1;
            st.z = *(unsigned int*)&h2; st.w = *(unsigned int*)&h3;
            *(uint4*)(agg + (size_t)n * 16 + q * 8) = st;   // 16B/lane
        }
    }
}

// ---------------------------------------------------------------------------
// C. MLP (R9/R10-verified): fused two-phase, 8 waves per 64-node tile.
//    Phase A: wave ws computes h[k=ws*16..+15] (k wave-uniform -> W1t on the
//    scalar pipe), h-pairs f16 in LDS H2[kp][node]. Phase B: wave ws
//    computes outs o=ws*4..+3 from H2 + s_load'ed W2t. 12500 waves.
// ---------------------------------------------------------------------------
__global__ __launch_bounds__(512, 4) void mlp_kernel(
    const float* __restrict__ x, const __half* __restrict__ agg,
    const float* __restrict__ W1t, const float* __restrict__ b1,
    const float* __restrict__ W2t, const float* __restrict__ b2,
    float* __restrict__ out, int N) {
    __shared__ __half2 H2[64 * 64];   // [kp][node], 16 KB
    int tid  = threadIdx.x;
    int lane = tid & 63;
    int ws   = __builtin_amdgcn_readfirstlane(tid >> 6);
    int n    = blockIdx.x * 64 + lane;
    int nc   = min(n, N - 1);

    float comb[32];
    const float4* xr = (const float4*)(x + (size_t)nc * 32);
    #pragma unroll
    for (int c = 0; c < 4; c++) {
        float4 v = xr[c];
        comb[c*4+0] = v.x; comb[c*4+1] = v.y;
        comb[c*4+2] = v.z; comb[c*4+3] = v.w;
    }
    const __half2* ar = (const __half2*)(agg + (size_t)nc * 16);
    #pragma unroll
    for (int c = 0; c < 8; c++) {
        float2 f = __half22float2(ar[c]);
        comb[16 + 2*c]     = f.x;
        comb[16 + 2*c + 1] = f.y;
    }

    #pragma unroll
    for (int i = 0; i < 16; i += 2) {
        int k0 = ws * 16 + i;
        const float* w1a = W1t + k0 * 32;
        const float* w1b = w1a + 32;
        float ha = b1[k0], hb = b1[k0 + 1];
        #pragma unroll
        for (int c = 0; c < 32; c++) {
            ha = fmaf(comb[c], w1a[c], ha);
            hb = fmaf(comb[c], w1b[c], hb);
        }
        ha = fmaxf(ha, 0.f); hb = fmaxf(hb, 0.f);
        H2[(k0 >> 1) * 64 + lane] = __floats2half2_rn(ha, hb);
    }
    __syncthreads();

    int o0 = ws * 4;
    const float* w20 = W2t + (o0 + 0) * 128;
    const float* w21 = W2t + (o0 + 1) * 128;
    const float* w22 = W2t + (o0 + 2) * 128;
    const float* w23 = W2t + (o0 + 3) * 128;
    float acc0 = b2[o0+0], acc1 = b2[o0+1], acc2 = b2[o0+2], acc3 = b2[o0+3];
    #pragma unroll 8
    for (int kp = 0; kp < 64; kp++) {
        float2 h = __half22float2(H2[kp * 64 + lane]);
        int k0 = 2 * kp;
        acc0 = fmaf(h.x, w20[k0], acc0); acc0 = fmaf(h.y, w20[k0+1], acc0);
        acc1 = fmaf(h.x, w21[k0], acc1); acc1 = fmaf(h.y, w21[k0+1], acc1);
        acc2 = fmaf(h.x, w22[k0], acc2); acc2 = fmaf(h.y, w22[k0+1], acc2);
        acc3 = fmaf(h.x, w23[k0], acc3); acc3 = fmaf(h.y, w23[k0+1], acc3);
    }
    if (n < N) {
        float* op = out + (size_t)n * 32 + o0;
        op[0] = acc0; op[1] = acc1; op[2] = acc2; op[3] = acc3;
    }
}

extern "C" void kernel_launch(void* const* d_in, const int* in_sizes, int n_in,
                              void* d_out, int out_size, void* d_ws, size_t ws_size,
                              hipStream_t stream) {
    const float* x   = (const float*)d_in[0];
    const int*   idx = (const int*)d_in[1];
    const float* W1  = (const float*)d_in[2];
    const float* b1  = (const float*)d_in[3];
    const float* W2  = (const float*)d_in[4];
    const float* b2  = (const float*)d_in[5];
    float* out = (float*)d_out;

    const int E = in_sizes[1] / 2;     // 1,600,000
    const int total = 2 * E;           // 3,200,000
    const int chunk = (total + NBLK_A - 1) / NBLK_A;   // 12,500

    // ws layout (~45.3 MB of the 256 MiB workspace):
    //   agg f16 3.2MB | xcon f16 3.2MB | W1t 16KB | W2t 16KB |
    //   cnts 400KB | binned 391*24576*4 = 38.4MB
    char* base = (char*)d_ws;
    __half*       agg    = (__half*)base;
    __half*       xcon   = (__half*)(base + 3203072);
    float*        W1t    = (float*)(base + 6406144);
    float*        W2t    = (float*)(base + 6422528);
    int*          cnts   = (int*)(base + 6438912);
    unsigned int* binned = (unsigned int*)(base + 6839296);

    int pack_blocks = (N_NODES * 8 + BTHR - 1) / BTHR;   // 1563
    binfuse_kernel<<<NBLK_A + 1 + pack_blocks, BTHR, 0, stream>>>(
        idx, x, (__half2*)xcon, W1, W2, W1t, W2t,
        binned, cnts, chunk, total, E);
    agg_kernel<<<NBKT, 1024, 0, stream>>>(xcon, cnts, binned, agg);
    mlp_kernel<<<(N_NODES + 63) / 64, 512, 0, stream>>>(
        x, agg, W1t, b1, W2t, b2, out, N_NODES);
}